// Round 5
// baseline (113.486 us; speedup 1.0000x reference)
//
#include <hip/hip_runtime.h>
#include <cstdint>

#define CC 1000
#define KK 2
#define DD 128

typedef short bf16x8 __attribute__((ext_vector_type(8)));
typedef float f32x16 __attribute__((ext_vector_type(16)));
typedef int   i32x4  __attribute__((ext_vector_type(4)));

__device__ __forceinline__ uint32_t f2bf(float f) {
    uint32_t x = __builtin_bit_cast(uint32_t, f);
    return (x + 0x7FFFu + ((x >> 16) & 1u)) >> 16;
}
__device__ __forceinline__ uint32_t pk2(float lo, float hi) {
    return f2bf(lo) | (f2bf(hi) << 16);
}
__device__ __forceinline__ f32x16 zero16() {
    f32x16 v;
    #pragma unroll
    for (int p = 0; p < 16; ++p) v[p] = 0.f;
    return v;
}
__device__ __forceinline__ bf16x8 mk_frag(const uint32_t* wv) {
    i32x4 t;
    t[0] = (int)wv[0]; t[1] = (int)wv[1]; t[2] = (int)wv[2]; t[3] = (int)wv[3];
    return __builtin_bit_cast(bf16x8, t);
}

// C-layout fp32 tile -> 8 packed-bf16 B-fragment words.
// Lane (col n=l31, half hp) holds rows (p&3)+8*(p>>2)+4*hp. B-frag word j for step s
// needs rows {16s+8hp+2j, +1}; half of those live in the partner lane (l^32).
__device__ __forceinline__ void build_frags(const f32x16& t, uint32_t* out, int hp) {
    uint32_t W[8];
    #pragma unroll
    for (int q = 0; q < 8; ++q) W[q] = pk2(t[2*q], t[2*q+1]);
    uint32_t s0 = (uint32_t)__shfl_xor((int)W[0], 32, 64);
    uint32_t s1 = (uint32_t)__shfl_xor((int)W[1], 32, 64);
    uint32_t s2 = (uint32_t)__shfl_xor((int)W[2], 32, 64);
    uint32_t s3 = (uint32_t)__shfl_xor((int)W[3], 32, 64);
    uint32_t s4 = (uint32_t)__shfl_xor((int)W[4], 32, 64);
    uint32_t s5 = (uint32_t)__shfl_xor((int)W[5], 32, 64);
    uint32_t s6 = (uint32_t)__shfl_xor((int)W[6], 32, 64);
    uint32_t s7 = (uint32_t)__shfl_xor((int)W[7], 32, 64);
    out[0] = hp ? s2   : W[0];
    out[1] = hp ? s3   : W[1];
    out[2] = hp ? W[2] : s0;
    out[3] = hp ? W[3] : s1;
    out[4] = hp ? s6   : W[4];
    out[5] = hp ? s7   : W[5];
    out[6] = hp ? W[6] : s4;
    out[7] = hp ? W[7] : s5;
}

// LDS layout (bytes, 16B-aligned, rows stride 80B = bank-spread):
//   [0,15360)      Eoff: 6 off-diag blocks, A-layout, holds -L_ij
//   [15360,25600)  Sm:   4 diag blocks, first -S_i, overwritten by M'_i
//   [25600,35840)  Tt:   4 diag blocks, (I - S_i) transposed (B-layout)
__global__ __launch_bounds__(512, 4)
__attribute__((amdgpu_waves_per_eu(4, 4)))   // pin 4 waves/EU -> 128-VGPR budget, no scratch
void mda_kernel(
    const float* __restrict__ z,          // (B, D)
    const float* __restrict__ mu,         // (C, K, D)
    const float* __restrict__ logits_pi,  // (C, K)
    const float* __restrict__ covL,       // (C, K, D, D)
    const float* __restrict__ prior,      // (C,)
    float* __restrict__ out)              // (B, C)
{
    __shared__ __align__(16) char E[35840];
    __shared__ float RD[DD];
    __shared__ float LG[2];

    const int c   = blockIdx.x;
    const int tid = threadIdx.x;
    const int w   = tid >> 6, l = tid & 63, l31 = l & 31, hp = l >> 5;
    const int bcol = w * 32 + l31;              // this lane's batch column
    const float* zb = z + (size_t)bcol * DD;

    float lp0 = 0.f, lp1 = 0.f;

    for (int k = 0; k < KK; ++k) {
        const float* Lm  = covL + (int64_t)(c*KK + k) * (DD*DD);
        const float* muv = mu + (size_t)(c*KK + k) * DD;

        // ---- phase A: rdiag + logdet (waves 0,1)
        if (tid < DD) {
            float dg = Lm[(size_t)tid * DD + tid];
            RD[tid] = 1.0f / dg;
            float lg = __logf(dg);
            #pragma unroll
            for (int o = 32; o; o >>= 1) lg += __shfl_down(lg, o, 64);
            if (l == 0) LG[tid >> 6] = lg;
        }
        __syncthreads();
        const float sld = LG[0] + LG[1];

        // ---- phase B: stage E (coalesced float4 row loads, one conversion total)
        {
            const int bi[6] = {1,2,2,3,3,3}, bj[6] = {0,0,1,0,1,2};
            #pragma unroll
            for (int rep = 0; rep < 3; ++rep) {  // 6 blocks * 32 rows * 8 float4
                int t2 = tid + 512*rep;
                int blk = t2 >> 8, r = (t2 >> 3) & 31, c4 = t2 & 7;
                float4 v = *(const float4*)(Lm + (size_t)(32*bi[blk] + r)*DD + 32*bj[blk] + 4*c4);
                uint2 u; u.x = pk2(-v.x, -v.y); u.y = pk2(-v.z, -v.w);
                *(uint2*)(E + blk*2560 + r*80 + 8*c4) = u;
            }
            #pragma unroll
            for (int rep = 0; rep < 2; ++rep) {  // 4 diag blocks * 32 * 8
                int t3 = tid + 512*rep;
                int ib = t3 >> 8, r = (t3 >> 3) & 31, c4 = t3 & 7;
                float4 v = *(const float4*)(Lm + (size_t)(32*ib + r)*DD + 32*ib + 4*c4);
                float rdr = RD[32*ib + r];
                float vv[4] = {v.x, v.y, v.z, v.w};
                float sm[4];
                #pragma unroll
                for (int e = 0; e < 4; ++e) {
                    int n = 4*c4 + e;
                    float se = (n < r) ? -vv[e]*rdr : 0.f;
                    sm[e] = se;
                    float tv = (n == r) ? 1.f : se;      // (I - S)[r][n]
                    *(unsigned short*)(E + 25600 + ib*2560 + n*80 + 2*r) = (unsigned short)f2bf(tv);
                }
                uint2 u; u.x = pk2(sm[0], sm[1]); u.y = pk2(sm[2], sm[3]);
                *(uint2*)(E + 15360 + ib*2560 + r*80 + 8*c4) = u;
            }
        }
        __syncthreads();

        // ---- M' compute: wave w<4 owns tile w.  M' = (I + (-S)(I-S)) * D^-1
        if (w < 4) {
            const char* SmB = E + 15360 + w*2560;
            const char* TtB = E + 25600 + w*2560;
            bf16x8 A0 = *(const bf16x8*)(SmB + l31*80 + 16*hp);
            bf16x8 A1 = *(const bf16x8*)(SmB + l31*80 + 32 + 16*hp);
            bf16x8 B0 = *(const bf16x8*)(TtB + l31*80 + 16*hp);
            bf16x8 B1 = *(const bf16x8*)(TtB + l31*80 + 32 + 16*hp);
            f32x16 mm = zero16();
            mm = __builtin_amdgcn_mfma_f32_32x32x16_bf16(A0, B0, mm, 0,0,0);
            mm = __builtin_amdgcn_mfma_f32_32x32x16_bf16(A1, B1, mm, 0,0,0);
            float rdn = RD[32*w + l31];          // column scale (n = l31)
            char* SmW = E + 15360 + w*2560;
            #pragma unroll
            for (int p = 0; p < 16; ++p) {
                int rowp = (p&3) + 8*(p>>2) + 4*hp;
                float mval = (mm[p] + ((rowp == l31) ? 1.f : 0.f)) * rdn;
                *(unsigned short*)(SmW + rowp*80 + 2*l31) = (unsigned short)f2bf(mval);
            }
        }
        __syncthreads();

        // ---- solve: per wave, 32 batch cols, everything in registers
        uint32_t yW[3][8];
        float macc = 0.f;
        #pragma unroll
        for (int i = 0; i < 4; ++i) {
            f32x16 acc;
            #pragma unroll
            for (int q = 0; q < 4; ++q) {        // r_i fp32 straight from z/mu (C-layout)
                float4 zv = *(const float4*)(zb + 32*i + 8*q + 4*hp);
                float4 mv = *(const float4*)(muv + 32*i + 8*q + 4*hp);
                acc[4*q+0] = zv.x - mv.x;
                acc[4*q+1] = zv.y - mv.y;
                acc[4*q+2] = zv.z - mv.z;
                acc[4*q+3] = zv.w - mv.w;
            }
            #pragma unroll
            for (int j = 0; j < i; ++j) {        // t_i = r_i - sum_j L_ij y_j
                const char* Ep = E + (i*(i-1)/2 + j)*2560 + l31*80 + 16*hp;
                bf16x8 A0 = *(const bf16x8*)(Ep);
                bf16x8 A1 = *(const bf16x8*)(Ep + 32);
                acc = __builtin_amdgcn_mfma_f32_32x32x16_bf16(A0, mk_frag(&yW[j][0]), acc, 0,0,0);
                acc = __builtin_amdgcn_mfma_f32_32x32x16_bf16(A1, mk_frag(&yW[j][4]), acc, 0,0,0);
            }
            uint32_t tF[8];
            build_frags(acc, tF, hp);            // t -> bf16 B-frags, no LDS
            const char* Mp = E + 15360 + i*2560 + l31*80 + 16*hp;
            bf16x8 MA0 = *(const bf16x8*)(Mp);
            bf16x8 MA1 = *(const bf16x8*)(Mp + 32);
            f32x16 yv = zero16();                // y_i = M'_i t_i
            yv = __builtin_amdgcn_mfma_f32_32x32x16_bf16(MA0, mk_frag(&tF[0]), yv, 0,0,0);
            yv = __builtin_amdgcn_mfma_f32_32x32x16_bf16(MA1, mk_frag(&tF[4]), yv, 0,0,0);
            #pragma unroll
            for (int p = 0; p < 16; ++p) macc += yv[p] * yv[p];
            if (i < 3) build_frags(yv, yW[i], hp);
        }
        macc += __shfl_xor(macc, 32, 64);        // combine row-halves per column

        const float CST = 235.2482645f;          // 128*log(2*pi)
        float lp = -0.5f * (macc + 2.f * sld + CST);
        if (k == 0) lp0 = lp; else lp1 = lp;
    }

    // ---- epilogue: prior + LSE_k(lp + logpi) - LSE_k(logpi)
    if (hp == 0) {
        float pi0 = logits_pi[c*2+0], pi1 = logits_pi[c*2+1];
        float mp = fmaxf(pi0, pi1);
        float lsepi = mp + __logf(__expf(pi0-mp) + __expf(pi1-mp));
        float t0 = lp0 + pi0, t1 = lp1 + pi1;
        float mt = fmaxf(t0, t1);
        float v = prior[c] + mt + __logf(__expf(t0-mt) + __expf(t1-mt)) - lsepi;
        out[(size_t)bcol * CC + c] = v;
    }
}

extern "C" void kernel_launch(void* const* d_in, const int* in_sizes, int n_in,
                              void* d_out, int out_size, void* d_ws, size_t ws_size,
                              hipStream_t stream) {
    const float* z         = (const float*)d_in[0];
    const float* mu        = (const float*)d_in[1];
    const float* logits_pi = (const float*)d_in[2];
    const float* covL      = (const float*)d_in[3];
    const float* prior     = (const float*)d_in[4];
    float* out = (float*)d_out;

    hipLaunchKernelGGL(mda_kernel, dim3(CC), dim3(512), 0, stream,
                       z, mu, logits_pi, covL, prior, out);
}

// Round 6
// 112.568 us; speedup vs baseline: 1.0082x; 1.0082x over previous
//
#include <hip/hip_runtime.h>
#include <cstdint>

#define CC 1000
#define KK 2
#define DD 128

typedef short bf16x8 __attribute__((ext_vector_type(8)));
typedef float f32x16 __attribute__((ext_vector_type(16)));
typedef int   i32x4  __attribute__((ext_vector_type(4)));

__device__ __forceinline__ uint32_t f2bf(float f) {
    uint32_t x = __builtin_bit_cast(uint32_t, f);
    return (x + 0x7FFFu + ((x >> 16) & 1u)) >> 16;
}
__device__ __forceinline__ uint32_t pk2(float lo, float hi) {
    return f2bf(lo) | (f2bf(hi) << 16);
}
__device__ __forceinline__ f32x16 zero16() {
    f32x16 v;
    #pragma unroll
    for (int p = 0; p < 16; ++p) v[p] = 0.f;
    return v;
}
__device__ __forceinline__ bf16x8 mk_frag(const uint32_t* wv) {
    i32x4 t;
    t[0] = (int)wv[0]; t[1] = (int)wv[1]; t[2] = (int)wv[2]; t[3] = (int)wv[3];
    return __builtin_bit_cast(bf16x8, t);
}

// C-layout fp32 tile -> 8 packed-bf16 B-fragment words.
// Lane (col n=l31, half hp) holds rows (p&3)+8*(p>>2)+4*hp. B-frag word j for step s
// needs rows {16s+8hp+2j, +1}; half of those live in the partner lane (l^32).
__device__ __forceinline__ void build_frags(const f32x16& t, uint32_t* out, int hp) {
    uint32_t W[8];
    #pragma unroll
    for (int q = 0; q < 8; ++q) W[q] = pk2(t[2*q], t[2*q+1]);
    uint32_t s0 = (uint32_t)__shfl_xor((int)W[0], 32, 64);
    uint32_t s1 = (uint32_t)__shfl_xor((int)W[1], 32, 64);
    uint32_t s2 = (uint32_t)__shfl_xor((int)W[2], 32, 64);
    uint32_t s3 = (uint32_t)__shfl_xor((int)W[3], 32, 64);
    uint32_t s4 = (uint32_t)__shfl_xor((int)W[4], 32, 64);
    uint32_t s5 = (uint32_t)__shfl_xor((int)W[5], 32, 64);
    uint32_t s6 = (uint32_t)__shfl_xor((int)W[6], 32, 64);
    uint32_t s7 = (uint32_t)__shfl_xor((int)W[7], 32, 64);
    out[0] = hp ? s2   : W[0];
    out[1] = hp ? s3   : W[1];
    out[2] = hp ? W[2] : s0;
    out[3] = hp ? W[3] : s1;
    out[4] = hp ? s6   : W[4];
    out[5] = hp ? s7   : W[5];
    out[6] = hp ? W[6] : s4;
    out[7] = hp ? W[7] : s5;
}

// LDS layout (bytes, 16B-aligned, rows stride 80B = bank-spread):
//   [0,15360)      Eoff: 6 off-diag blocks, A-layout, holds -L_ij
//   [15360,25600)  Sm:   4 diag blocks, first -S_i, overwritten by M'_i
//   [25600,35840)  Tt:   4 diag blocks, (I - S_i) transposed (B-layout)
// NOTE: __launch_bounds__ has NO second arg — a second arg emits its own
// amdgpu-waves-per-eu(min) and clang drops the explicit attribute below,
// leaving the backend free to target 8 waves/EU with a 64-VGPR budget
// (round-5 evidence: VGPR_Count=64, 131 MB scratch writes).
__global__ __launch_bounds__(512)
__attribute__((amdgpu_waves_per_eu(4, 4)))   // exactly 4 waves/EU -> 128-VGPR budget
void mda_kernel(
    const float* __restrict__ z,          // (B, D)
    const float* __restrict__ mu,         // (C, K, D)
    const float* __restrict__ logits_pi,  // (C, K)
    const float* __restrict__ covL,       // (C, K, D, D)
    const float* __restrict__ prior,      // (C,)
    float* __restrict__ out)              // (B, C)
{
    __shared__ __align__(16) char E[35840];
    __shared__ float RD[DD];
    __shared__ float LG[2];

    const int c   = blockIdx.x;
    const int tid = threadIdx.x;
    const int w   = tid >> 6, l = tid & 63, l31 = l & 31, hp = l >> 5;
    const int bcol = w * 32 + l31;              // this lane's batch column
    const float* zb = z + (size_t)bcol * DD;

    float lp0 = 0.f, lp1 = 0.f;

    for (int k = 0; k < KK; ++k) {
        const float* Lm  = covL + (int64_t)(c*KK + k) * (DD*DD);
        const float* muv = mu + (size_t)(c*KK + k) * DD;

        // ---- phase A: rdiag + logdet (waves 0,1)
        if (tid < DD) {
            float dg = Lm[(size_t)tid * DD + tid];
            RD[tid] = 1.0f / dg;
            float lg = __logf(dg);
            #pragma unroll
            for (int o = 32; o; o >>= 1) lg += __shfl_down(lg, o, 64);
            if (l == 0) LG[tid >> 6] = lg;
        }
        __syncthreads();
        const float sld = LG[0] + LG[1];

        // ---- phase B: stage E (coalesced float4 row loads, one conversion total)
        {
            const int bi[6] = {1,2,2,3,3,3}, bj[6] = {0,0,1,0,1,2};
            #pragma unroll
            for (int rep = 0; rep < 3; ++rep) {  // 6 blocks * 32 rows * 8 float4
                int t2 = tid + 512*rep;
                int blk = t2 >> 8, r = (t2 >> 3) & 31, c4 = t2 & 7;
                float4 v = *(const float4*)(Lm + (size_t)(32*bi[blk] + r)*DD + 32*bj[blk] + 4*c4);
                uint2 u; u.x = pk2(-v.x, -v.y); u.y = pk2(-v.z, -v.w);
                *(uint2*)(E + blk*2560 + r*80 + 8*c4) = u;
            }
            #pragma unroll
            for (int rep = 0; rep < 2; ++rep) {  // 4 diag blocks * 32 * 8
                int t3 = tid + 512*rep;
                int ib = t3 >> 8, r = (t3 >> 3) & 31, c4 = t3 & 7;
                float4 v = *(const float4*)(Lm + (size_t)(32*ib + r)*DD + 32*ib + 4*c4);
                float rdr = RD[32*ib + r];
                float vv[4] = {v.x, v.y, v.z, v.w};
                float sm[4];
                #pragma unroll
                for (int e = 0; e < 4; ++e) {
                    int n = 4*c4 + e;
                    float se = (n < r) ? -vv[e]*rdr : 0.f;
                    sm[e] = se;
                    float tv = (n == r) ? 1.f : se;      // (I - S)[r][n]
                    *(unsigned short*)(E + 25600 + ib*2560 + n*80 + 2*r) = (unsigned short)f2bf(tv);
                }
                uint2 u; u.x = pk2(sm[0], sm[1]); u.y = pk2(sm[2], sm[3]);
                *(uint2*)(E + 15360 + ib*2560 + r*80 + 8*c4) = u;
            }
        }
        __syncthreads();

        // ---- M' compute: wave w<4 owns tile w.  M' = (I + (-S)(I-S)) * D^-1
        if (w < 4) {
            const char* SmB = E + 15360 + w*2560;
            const char* TtB = E + 25600 + w*2560;
            bf16x8 A0 = *(const bf16x8*)(SmB + l31*80 + 16*hp);
            bf16x8 A1 = *(const bf16x8*)(SmB + l31*80 + 32 + 16*hp);
            bf16x8 B0 = *(const bf16x8*)(TtB + l31*80 + 16*hp);
            bf16x8 B1 = *(const bf16x8*)(TtB + l31*80 + 32 + 16*hp);
            f32x16 mm = zero16();
            mm = __builtin_amdgcn_mfma_f32_32x32x16_bf16(A0, B0, mm, 0,0,0);
            mm = __builtin_amdgcn_mfma_f32_32x32x16_bf16(A1, B1, mm, 0,0,0);
            float rdn = RD[32*w + l31];          // column scale (n = l31)
            char* SmW = E + 15360 + w*2560;
            #pragma unroll
            for (int p = 0; p < 16; ++p) {
                int rowp = (p&3) + 8*(p>>2) + 4*hp;
                float mval = (mm[p] + ((rowp == l31) ? 1.f : 0.f)) * rdn;
                *(unsigned short*)(SmW + rowp*80 + 2*l31) = (unsigned short)f2bf(mval);
            }
        }
        __syncthreads();

        // ---- solve: per wave, 32 batch cols, everything in registers
        uint32_t yW[3][8];
        float macc = 0.f;
        #pragma unroll
        for (int i = 0; i < 4; ++i) {
            f32x16 acc;
            #pragma unroll
            for (int q = 0; q < 4; ++q) {        // r_i fp32 straight from z/mu (C-layout)
                float4 zv = *(const float4*)(zb + 32*i + 8*q + 4*hp);
                float4 mv = *(const float4*)(muv + 32*i + 8*q + 4*hp);
                acc[4*q+0] = zv.x - mv.x;
                acc[4*q+1] = zv.y - mv.y;
                acc[4*q+2] = zv.z - mv.z;
                acc[4*q+3] = zv.w - mv.w;
            }
            #pragma unroll
            for (int j = 0; j < i; ++j) {        // t_i = r_i - sum_j L_ij y_j
                const char* Ep = E + (i*(i-1)/2 + j)*2560 + l31*80 + 16*hp;
                bf16x8 A0 = *(const bf16x8*)(Ep);
                bf16x8 A1 = *(const bf16x8*)(Ep + 32);
                acc = __builtin_amdgcn_mfma_f32_32x32x16_bf16(A0, mk_frag(&yW[j][0]), acc, 0,0,0);
                acc = __builtin_amdgcn_mfma_f32_32x32x16_bf16(A1, mk_frag(&yW[j][4]), acc, 0,0,0);
            }
            uint32_t tF[8];
            build_frags(acc, tF, hp);            // t -> bf16 B-frags, no LDS
            const char* Mp = E + 15360 + i*2560 + l31*80 + 16*hp;
            bf16x8 MA0 = *(const bf16x8*)(Mp);
            bf16x8 MA1 = *(const bf16x8*)(Mp + 32);
            f32x16 yv = zero16();                // y_i = M'_i t_i
            yv = __builtin_amdgcn_mfma_f32_32x32x16_bf16(MA0, mk_frag(&tF[0]), yv, 0,0,0);
            yv = __builtin_amdgcn_mfma_f32_32x32x16_bf16(MA1, mk_frag(&tF[4]), yv, 0,0,0);
            #pragma unroll
            for (int p = 0; p < 16; ++p) macc += yv[p] * yv[p];
            if (i < 3) build_frags(yv, yW[i], hp);
        }
        macc += __shfl_xor(macc, 32, 64);        // combine row-halves per column

        const float CST = 235.2482645f;          // 128*log(2*pi)
        float lp = -0.5f * (macc + 2.f * sld + CST);
        if (k == 0) lp0 = lp; else lp1 = lp;
    }

    // ---- epilogue: prior + LSE_k(lp + logpi) - LSE_k(logpi)
    if (hp == 0) {
        float pi0 = logits_pi[c*2+0], pi1 = logits_pi[c*2+1];
        float mp = fmaxf(pi0, pi1);
        float lsepi = mp + __logf(__expf(pi0-mp) + __expf(pi1-mp));
        float t0 = lp0 + pi0, t1 = lp1 + pi1;
        float mt = fmaxf(t0, t1);
        float v = prior[c] + mt + __logf(__expf(t0-mt) + __expf(t1-mt)) - lsepi;
        out[(size_t)bcol * CC + c] = v;
    }
}

extern "C" void kernel_launch(void* const* d_in, const int* in_sizes, int n_in,
                              void* d_out, int out_size, void* d_ws, size_t ws_size,
                              hipStream_t stream) {
    const float* z         = (const float*)d_in[0];
    const float* mu        = (const float*)d_in[1];
    const float* logits_pi = (const float*)d_in[2];
    const float* covL      = (const float*)d_in[3];
    const float* prior     = (const float*)d_in[4];
    float* out = (float*)d_out;

    hipLaunchKernelGGL(mda_kernel, dim3(CC), dim3(512), 0, stream,
                       z, mu, logits_pi, covL, prior, out);
}

// Round 7
// 110.469 us; speedup vs baseline: 1.0273x; 1.0190x over previous
//
#include <hip/hip_runtime.h>
#include <cstdint>

#define CC 1000
#define KK 2
#define DD 128

typedef short bf16x8 __attribute__((ext_vector_type(8)));
typedef float f32x16 __attribute__((ext_vector_type(16)));
typedef int   i32x4  __attribute__((ext_vector_type(4)));

__device__ __forceinline__ uint32_t f2bf(float f) {
    uint32_t x = __builtin_bit_cast(uint32_t, f);
    return (x + 0x7FFFu + ((x >> 16) & 1u)) >> 16;
}
__device__ __forceinline__ uint32_t pk2(float lo, float hi) {
    return f2bf(lo) | (f2bf(hi) << 16);
}
__device__ __forceinline__ f32x16 zero16() {
    f32x16 v;
    #pragma unroll
    for (int p = 0; p < 16; ++p) v[p] = 0.f;
    return v;
}

// 8 packed-bf16 words = one 32x32x16 B-fragment pair, fully scalarized
// (named fields only; never indexed, never address-taken -> SROA-proof).
struct Frag8 { uint32_t a0, a1, a2, a3, b0, b1, b2, b3; };

__device__ __forceinline__ bf16x8 flo(const Frag8 f) {
    i32x4 t; t[0] = (int)f.a0; t[1] = (int)f.a1; t[2] = (int)f.a2; t[3] = (int)f.a3;
    return __builtin_bit_cast(bf16x8, t);
}
__device__ __forceinline__ bf16x8 fhi(const Frag8 f) {
    i32x4 t; t[0] = (int)f.b0; t[1] = (int)f.b1; t[2] = (int)f.b2; t[3] = (int)f.b3;
    return __builtin_bit_cast(bf16x8, t);
}

// C-layout fp32 tile -> B-fragment words. Lane (col n=l31, half hp) holds rows
// (p&3)+8*(p>>2)+4*hp; B-frag word j of step s needs rows {16s+8hp+2j,+1}; half
// live in partner lane (l^32). Identical mapping to the round-4..6 (passing) kernel.
__device__ __forceinline__ Frag8 build_frags(const f32x16 t, int hp) {
    uint32_t W0 = pk2(t[0],  t[1]),  W1 = pk2(t[2],  t[3]);
    uint32_t W2 = pk2(t[4],  t[5]),  W3 = pk2(t[6],  t[7]);
    uint32_t W4 = pk2(t[8],  t[9]),  W5 = pk2(t[10], t[11]);
    uint32_t W6 = pk2(t[12], t[13]), W7 = pk2(t[14], t[15]);
    uint32_t s0 = (uint32_t)__shfl_xor((int)W0, 32, 64);
    uint32_t s1 = (uint32_t)__shfl_xor((int)W1, 32, 64);
    uint32_t s2 = (uint32_t)__shfl_xor((int)W2, 32, 64);
    uint32_t s3 = (uint32_t)__shfl_xor((int)W3, 32, 64);
    uint32_t s4 = (uint32_t)__shfl_xor((int)W4, 32, 64);
    uint32_t s5 = (uint32_t)__shfl_xor((int)W5, 32, 64);
    uint32_t s6 = (uint32_t)__shfl_xor((int)W6, 32, 64);
    uint32_t s7 = (uint32_t)__shfl_xor((int)W7, 32, 64);
    Frag8 f;
    f.a0 = hp ? s2 : W0;  f.a1 = hp ? s3 : W1;
    f.a2 = hp ? W2 : s0;  f.a3 = hp ? W3 : s1;
    f.b0 = hp ? s6 : W4;  f.b1 = hp ? s7 : W5;
    f.b2 = hp ? W6 : s4;  f.b3 = hp ? W7 : s5;
    return f;
}

__device__ __forceinline__ f32x16 off_apply(const char* Ep, const Frag8 yj, f32x16 acc) {
    bf16x8 A0 = *(const bf16x8*)(Ep);
    bf16x8 A1 = *(const bf16x8*)(Ep + 32);
    acc = __builtin_amdgcn_mfma_f32_32x32x16_bf16(A0, flo(yj), acc, 0, 0, 0);
    acc = __builtin_amdgcn_mfma_f32_32x32x16_bf16(A1, fhi(yj), acc, 0, 0, 0);
    return acc;
}
__device__ __forceinline__ f32x16 m_solve(const char* Mp, const Frag8 tf) {
    bf16x8 MA0 = *(const bf16x8*)(Mp);
    bf16x8 MA1 = *(const bf16x8*)(Mp + 32);
    f32x16 y = zero16();
    y = __builtin_amdgcn_mfma_f32_32x32x16_bf16(MA0, flo(tf), y, 0, 0, 0);
    y = __builtin_amdgcn_mfma_f32_32x32x16_bf16(MA1, fhi(tf), y, 0, 0, 0);
    return y;
}

// LDS layout (rows stride 80B = bank-spread):
//   [0,15360)      Eoff: 6 off-diag blocks, A-layout, holds -L_ij
//   [15360,25600)  Sm:   4 diag blocks, first -S_i, overwritten by M'_i
//   [25600,35840)  Tt:   4 diag blocks, (I - S_i) transposed (B-layout)
//   [35840,56320)  PAD: forces LDS>160K/3 -> 2 blocks/CU -> backend occupancy
//                  target 4 waves/EU -> 128-VGPR budget (round-6: attr ignored,
//                  budget followed LDS-implied occupancy of 8 waves/EU -> 64).
__global__ __launch_bounds__(512)
__attribute__((amdgpu_waves_per_eu(4, 4)))
void mda_kernel(
    const float* __restrict__ z,          // (B, D)
    const float* __restrict__ mu,         // (C, K, D)
    const float* __restrict__ logits_pi,  // (C, K)
    const float* __restrict__ covL,       // (C, K, D, D)
    const float* __restrict__ prior,      // (C,)
    float* __restrict__ out)              // (B, C)
{
    __shared__ __align__(16) char E[56320];
    __shared__ float RD[DD];
    __shared__ float LG[2];

    const int c   = blockIdx.x;
    const int tid = threadIdx.x;
    const int w   = tid >> 6, l = tid & 63, l31 = l & 31, hp = l >> 5;
    const int bcol = w * 32 + l31;              // this lane's batch column
    const float* zb = z + (size_t)bcol * DD;
    const int off = l31 * 80 + 16 * hp;         // per-lane fragment offset in a block

    float lp0 = 0.f, lp1 = 0.f;

    for (int k = 0; k < KK; ++k) {
        const float* Lm  = covL + (int64_t)(c*KK + k) * (DD*DD);
        const float* muv = mu + (size_t)(c*KK + k) * DD;

        // ---- phase A: rdiag + logdet (waves 0,1)
        if (tid < DD) {
            float dg = Lm[(size_t)tid * DD + tid];
            RD[tid] = 1.0f / dg;
            float lg = __logf(dg);
            #pragma unroll
            for (int o = 32; o; o >>= 1) lg += __shfl_down(lg, o, 64);
            if (l == 0) LG[tid >> 6] = lg;
        }
        __syncthreads();
        const float sld = LG[0] + LG[1];

        // ---- phase B: stage E (coalesced float4 row loads, one conversion total)
        {
            #pragma unroll
            for (int rep = 0; rep < 3; ++rep) {  // 6 off-diag blocks * 32 rows * 8 float4
                int t2 = tid + 512*rep;
                int blk = t2 >> 8, r = (t2 >> 3) & 31, c4 = t2 & 7;
                // block list (i,j): (1,0)(2,0)(2,1)(3,0)(3,1)(3,2) — arithmetic, no LUT
                int ib = 1 + (blk >= 1) + (blk >= 3);
                int jb = blk - ((ib * (ib - 1)) >> 1);
                float4 v = *(const float4*)(Lm + (size_t)(32*ib + r)*DD + 32*jb + 4*c4);
                uint2 u; u.x = pk2(-v.x, -v.y); u.y = pk2(-v.z, -v.w);
                *(uint2*)(E + blk*2560 + r*80 + 8*c4) = u;
            }
            #pragma unroll
            for (int rep = 0; rep < 2; ++rep) {  // 4 diag blocks * 32 rows * 8 float4
                int t3 = tid + 512*rep;
                int ib = t3 >> 8, r = (t3 >> 3) & 31, c4 = t3 & 7;
                float4 v = *(const float4*)(Lm + (size_t)(32*ib + r)*DD + 32*ib + 4*c4);
                float rdr = RD[32*ib + r];
                int n0 = 4*c4;
                float se0 = (n0+0 < r) ? -v.x*rdr : 0.f;
                float se1 = (n0+1 < r) ? -v.y*rdr : 0.f;
                float se2 = (n0+2 < r) ? -v.z*rdr : 0.f;
                float se3 = (n0+3 < r) ? -v.w*rdr : 0.f;
                char* tt = E + 25600 + ib*2560 + 2*r;
                *(unsigned short*)(tt + (n0+0)*80) = (unsigned short)f2bf((n0+0 == r) ? 1.f : se0);
                *(unsigned short*)(tt + (n0+1)*80) = (unsigned short)f2bf((n0+1 == r) ? 1.f : se1);
                *(unsigned short*)(tt + (n0+2)*80) = (unsigned short)f2bf((n0+2 == r) ? 1.f : se2);
                *(unsigned short*)(tt + (n0+3)*80) = (unsigned short)f2bf((n0+3 == r) ? 1.f : se3);
                uint2 u; u.x = pk2(se0, se1); u.y = pk2(se2, se3);
                *(uint2*)(E + 15360 + ib*2560 + r*80 + 8*c4) = u;
            }
        }
        __syncthreads();

        // ---- M' compute: wave w<4 owns tile w.  M' = (I + (-S)(I-S)) * D^-1
        if (w < 4) {
            const char* SmB = E + 15360 + w*2560;
            const char* TtB = E + 25600 + w*2560;
            bf16x8 A0 = *(const bf16x8*)(SmB + l31*80 + 16*hp);
            bf16x8 A1 = *(const bf16x8*)(SmB + l31*80 + 32 + 16*hp);
            bf16x8 B0 = *(const bf16x8*)(TtB + l31*80 + 16*hp);
            bf16x8 B1 = *(const bf16x8*)(TtB + l31*80 + 32 + 16*hp);
            f32x16 mm = zero16();
            mm = __builtin_amdgcn_mfma_f32_32x32x16_bf16(A0, B0, mm, 0,0,0);
            mm = __builtin_amdgcn_mfma_f32_32x32x16_bf16(A1, B1, mm, 0,0,0);
            float rdn = RD[32*w + l31];          // column scale (n = l31)
            char* SmW = E + 15360 + w*2560;
            #pragma unroll
            for (int p = 0; p < 16; ++p) {
                int rowp = (p&3) + 8*(p>>2) + 4*hp;
                float mval = (mm[p] + ((rowp == l31) ? 1.f : 0.f)) * rdn;
                *(unsigned short*)(SmW + rowp*80 + 2*l31) = (unsigned short)f2bf(mval);
            }
        }
        __syncthreads();

        // ---- solve: hand-unrolled over the 4 row-tiles, zero local arrays
        float macc = 0.f;
        f32x16 acc, yv;
        Frag8 tf, y0, y1, y2;

        // r_i loader (i is a literal at every call site -> folds)
        #define LOAD_R(i)                                                        \
            do {                                                                 \
                _Pragma("unroll")                                                \
                for (int q = 0; q < 4; ++q) {                                    \
                    float4 zv = *(const float4*)(zb + 32*(i) + 8*q + 4*hp);      \
                    float4 mv = *(const float4*)(muv + 32*(i) + 8*q + 4*hp);     \
                    acc[4*q+0] = zv.x - mv.x;  acc[4*q+1] = zv.y - mv.y;         \
                    acc[4*q+2] = zv.z - mv.z;  acc[4*q+3] = zv.w - mv.w;         \
                }                                                                \
            } while (0)
        #define SQACC()                                                          \
            do {                                                                 \
                _Pragma("unroll")                                                \
                for (int p = 0; p < 16; ++p) macc += yv[p] * yv[p];              \
            } while (0)

        // i = 0
        LOAD_R(0);
        tf = build_frags(acc, hp);
        yv = m_solve(E + 15360 + 0*2560 + off, tf);
        SQACC();
        y0 = build_frags(yv, hp);
        // i = 1   (off-diag block (1,0) = blk 0)
        LOAD_R(1);
        acc = off_apply(E + 0*2560 + off, y0, acc);
        tf = build_frags(acc, hp);
        yv = m_solve(E + 15360 + 1*2560 + off, tf);
        SQACC();
        y1 = build_frags(yv, hp);
        // i = 2   (blocks (2,0)=1, (2,1)=2)
        LOAD_R(2);
        acc = off_apply(E + 1*2560 + off, y0, acc);
        acc = off_apply(E + 2*2560 + off, y1, acc);
        tf = build_frags(acc, hp);
        yv = m_solve(E + 15360 + 2*2560 + off, tf);
        SQACC();
        y2 = build_frags(yv, hp);
        // i = 3   (blocks (3,0)=3, (3,1)=4, (3,2)=5)
        LOAD_R(3);
        acc = off_apply(E + 3*2560 + off, y0, acc);
        acc = off_apply(E + 4*2560 + off, y1, acc);
        acc = off_apply(E + 5*2560 + off, y2, acc);
        tf = build_frags(acc, hp);
        yv = m_solve(E + 15360 + 3*2560 + off, tf);
        SQACC();
        #undef LOAD_R
        #undef SQACC

        macc += __shfl_xor(macc, 32, 64);        // combine row-halves per column

        const float CST = 235.2482645f;          // 128*log(2*pi)
        float lp = -0.5f * (macc + 2.f * sld + CST);
        if (k == 0) lp0 = lp; else lp1 = lp;
    }

    // ---- epilogue: prior + LSE_k(lp + logpi) - LSE_k(logpi)
    if (hp == 0) {
        float pi0 = logits_pi[c*2+0], pi1 = logits_pi[c*2+1];
        float mp = fmaxf(pi0, pi1);
        float lsepi = mp + __logf(__expf(pi0-mp) + __expf(pi1-mp));
        float t0 = lp0 + pi0, t1 = lp1 + pi1;
        float mt = fmaxf(t0, t1);
        float v = prior[c] + mt + __logf(__expf(t0-mt) + __expf(t1-mt)) - lsepi;
        out[(size_t)bcol * CC + c] = v;
    }
}

extern "C" void kernel_launch(void* const* d_in, const int* in_sizes, int n_in,
                              void* d_out, int out_size, void* d_ws, size_t ws_size,
                              hipStream_t stream) {
    const float* z         = (const float*)d_in[0];
    const float* mu        = (const float*)d_in[1];
    const float* logits_pi = (const float*)d_in[2];
    const float* covL      = (const float*)d_in[3];
    const float* prior     = (const float*)d_in[4];
    float* out = (float*)d_out;

    hipLaunchKernelGGL(mda_kernel, dim3(CC), dim3(512), 0, stream,
                       z, mu, logits_pi, covL, prior, out);
}

// Round 8
// 69.370 us; speedup vs baseline: 1.6360x; 1.5925x over previous
//
#include <hip/hip_runtime.h>
#include <cstdint>

#define CC 1000
#define KK 2
#define DD 128

typedef short bf16x8 __attribute__((ext_vector_type(8)));
typedef float f32x16 __attribute__((ext_vector_type(16)));
typedef int   i32x4  __attribute__((ext_vector_type(4)));

__device__ __forceinline__ uint32_t f2bf(float f) {
    uint32_t x = __builtin_bit_cast(uint32_t, f);
    return (x + 0x7FFFu + ((x >> 16) & 1u)) >> 16;
}
__device__ __forceinline__ uint32_t pk2(float lo, float hi) {
    return f2bf(lo) | (f2bf(hi) << 16);
}
__device__ __forceinline__ f32x16 zero16() {
    f32x16 v;
    #pragma unroll
    for (int p = 0; p < 16; ++p) v[p] = 0.f;
    return v;
}

// 8 packed-bf16 words = one 32x32x16 B-fragment pair, fully scalarized.
struct Frag8 { uint32_t a0, a1, a2, a3, b0, b1, b2, b3; };

__device__ __forceinline__ bf16x8 flo(const Frag8 f) {
    i32x4 t; t[0] = (int)f.a0; t[1] = (int)f.a1; t[2] = (int)f.a2; t[3] = (int)f.a3;
    return __builtin_bit_cast(bf16x8, t);
}
__device__ __forceinline__ bf16x8 fhi(const Frag8 f) {
    i32x4 t; t[0] = (int)f.b0; t[1] = (int)f.b1; t[2] = (int)f.b2; t[3] = (int)f.b3;
    return __builtin_bit_cast(bf16x8, t);
}

// C-layout fp32 tile -> B-fragment words (mapping verified in rounds 4..7).
__device__ __forceinline__ Frag8 build_frags(const f32x16 t, int hp) {
    uint32_t W0 = pk2(t[0],  t[1]),  W1 = pk2(t[2],  t[3]);
    uint32_t W2 = pk2(t[4],  t[5]),  W3 = pk2(t[6],  t[7]);
    uint32_t W4 = pk2(t[8],  t[9]),  W5 = pk2(t[10], t[11]);
    uint32_t W6 = pk2(t[12], t[13]), W7 = pk2(t[14], t[15]);
    uint32_t s0 = (uint32_t)__shfl_xor((int)W0, 32, 64);
    uint32_t s1 = (uint32_t)__shfl_xor((int)W1, 32, 64);
    uint32_t s2 = (uint32_t)__shfl_xor((int)W2, 32, 64);
    uint32_t s3 = (uint32_t)__shfl_xor((int)W3, 32, 64);
    uint32_t s4 = (uint32_t)__shfl_xor((int)W4, 32, 64);
    uint32_t s5 = (uint32_t)__shfl_xor((int)W5, 32, 64);
    uint32_t s6 = (uint32_t)__shfl_xor((int)W6, 32, 64);
    uint32_t s7 = (uint32_t)__shfl_xor((int)W7, 32, 64);
    Frag8 f;
    f.a0 = hp ? s2 : W0;  f.a1 = hp ? s3 : W1;
    f.a2 = hp ? W2 : s0;  f.a3 = hp ? W3 : s1;
    f.b0 = hp ? s6 : W4;  f.b1 = hp ? s7 : W5;
    f.b2 = hp ? W6 : s4;  f.b3 = hp ? W7 : s5;
    return f;
}

__device__ __forceinline__ f32x16 off_apply(const char* Ep, const Frag8 yj, f32x16 acc) {
    bf16x8 A0 = *(const bf16x8*)(Ep);
    bf16x8 A1 = *(const bf16x8*)(Ep + 32);
    acc = __builtin_amdgcn_mfma_f32_32x32x16_bf16(A0, flo(yj), acc, 0, 0, 0);
    acc = __builtin_amdgcn_mfma_f32_32x32x16_bf16(A1, fhi(yj), acc, 0, 0, 0);
    return acc;
}
__device__ __forceinline__ f32x16 m_solve(const char* Mp, const Frag8 tf) {
    bf16x8 MA0 = *(const bf16x8*)(Mp);
    bf16x8 MA1 = *(const bf16x8*)(Mp + 32);
    f32x16 y = zero16();
    y = __builtin_amdgcn_mfma_f32_32x32x16_bf16(MA0, flo(tf), y, 0, 0, 0);
    y = __builtin_amdgcn_mfma_f32_32x32x16_bf16(MA1, fhi(tf), y, 0, 0, 0);
    return y;
}

// LDS layout (rows stride 80B = bank-spread):
//   [0,15360)      Eoff: 6 off-diag blocks, A-layout, holds -L_ij
//   [15360,25600)  Sm:   4 diag blocks, first -S_i, overwritten by M'_i
//   [25600,35840)  Tt:   4 diag blocks, (I - S_i) transposed (B-layout)
//
// OCCUPANCY RECIPE (empirical, this session): __launch_bounds__(256, 1).
// Round-2 evidence: (256,1) -> VGPR_Count=164, WRITE_SIZE=8MB (spill-free).
// Rounds 4-7: 512-thread kernels always got a 64-VGPR budget (8 waves/EU
// target) regardless of amdgpu_waves_per_eu(4,4) or LDS padding -> 135 MB
// scratch. The backend relaxes occupancy only toward launch_bounds' 2nd arg.
__global__ __launch_bounds__(256, 1) void mda_kernel(
    const float* __restrict__ z,          // (B, D)
    const float* __restrict__ mu,         // (C, K, D)
    const float* __restrict__ logits_pi,  // (C, K)
    const float* __restrict__ covL,       // (C, K, D, D)
    const float* __restrict__ prior,      // (C,)
    float* __restrict__ out)              // (B, C)
{
    __shared__ __align__(16) char E[35840];
    __shared__ float RD[DD];
    __shared__ float LG[2];

    const int bid = blockIdx.x;
    const int c   = bid % CC;
    const int h   = bid / CC;                   // batch half (0,1)
    const int tid = threadIdx.x;
    const int w   = tid >> 6, l = tid & 63, l31 = l & 31, hp = l >> 5;
    const int bcol = h * 128 + w * 32 + l31;    // this lane's batch column
    const float* zb = z + (size_t)bcol * DD;
    const int off = l31 * 80 + 16 * hp;         // per-lane fragment offset in a block

    float lp0 = 0.f, lp1 = 0.f;

    for (int k = 0; k < KK; ++k) {
        const float* Lm  = covL + (int64_t)(c*KK + k) * (DD*DD);
        const float* muv = mu + (size_t)(c*KK + k) * DD;

        // ---- phase A: rdiag + logdet (waves 0,1)
        if (tid < DD) {
            float dg = Lm[(size_t)tid * DD + tid];
            RD[tid] = 1.0f / dg;
            float lg = __logf(dg);
            #pragma unroll
            for (int o = 32; o; o >>= 1) lg += __shfl_down(lg, o, 64);
            if (l == 0) LG[tid >> 6] = lg;
        }
        __syncthreads();
        const float sld = LG[0] + LG[1];

        // ---- phase B: stage E (coalesced float4 row loads; 256-thread indexing)
        {
            #pragma unroll
            for (int rep = 0; rep < 6; ++rep) {  // 6 off-diag blocks * 32 rows * 8 float4
                int t2 = tid + 256*rep;
                int blk = t2 >> 8, r = (t2 >> 3) & 31, c4 = t2 & 7;
                // block list (i,j): (1,0)(2,0)(2,1)(3,0)(3,1)(3,2)
                int ib = 1 + (blk >= 1) + (blk >= 3);
                int jb = blk - ((ib * (ib - 1)) >> 1);
                float4 v = *(const float4*)(Lm + (size_t)(32*ib + r)*DD + 32*jb + 4*c4);
                uint2 u; u.x = pk2(-v.x, -v.y); u.y = pk2(-v.z, -v.w);
                *(uint2*)(E + blk*2560 + r*80 + 8*c4) = u;
            }
            #pragma unroll
            for (int rep = 0; rep < 4; ++rep) {  // 4 diag blocks * 32 rows * 8 float4
                int t3 = tid + 256*rep;
                int ib = t3 >> 8, r = (t3 >> 3) & 31, c4 = t3 & 7;
                float4 v = *(const float4*)(Lm + (size_t)(32*ib + r)*DD + 32*ib + 4*c4);
                float rdr = RD[32*ib + r];
                int n0 = 4*c4;
                float se0 = (n0+0 < r) ? -v.x*rdr : 0.f;
                float se1 = (n0+1 < r) ? -v.y*rdr : 0.f;
                float se2 = (n0+2 < r) ? -v.z*rdr : 0.f;
                float se3 = (n0+3 < r) ? -v.w*rdr : 0.f;
                char* tt = E + 25600 + ib*2560 + 2*r;
                *(unsigned short*)(tt + (n0+0)*80) = (unsigned short)f2bf((n0+0 == r) ? 1.f : se0);
                *(unsigned short*)(tt + (n0+1)*80) = (unsigned short)f2bf((n0+1 == r) ? 1.f : se1);
                *(unsigned short*)(tt + (n0+2)*80) = (unsigned short)f2bf((n0+2 == r) ? 1.f : se2);
                *(unsigned short*)(tt + (n0+3)*80) = (unsigned short)f2bf((n0+3 == r) ? 1.f : se3);
                uint2 u; u.x = pk2(se0, se1); u.y = pk2(se2, se3);
                *(uint2*)(E + 15360 + ib*2560 + r*80 + 8*c4) = u;
            }
        }
        __syncthreads();

        // ---- M' compute: wave w owns tile w.  M' = (I + (-S)(I-S)) * D^-1
        {
            const char* SmB = E + 15360 + w*2560;
            const char* TtB = E + 25600 + w*2560;
            bf16x8 A0 = *(const bf16x8*)(SmB + l31*80 + 16*hp);
            bf16x8 A1 = *(const bf16x8*)(SmB + l31*80 + 32 + 16*hp);
            bf16x8 B0 = *(const bf16x8*)(TtB + l31*80 + 16*hp);
            bf16x8 B1 = *(const bf16x8*)(TtB + l31*80 + 32 + 16*hp);
            f32x16 mm = zero16();
            mm = __builtin_amdgcn_mfma_f32_32x32x16_bf16(A0, B0, mm, 0,0,0);
            mm = __builtin_amdgcn_mfma_f32_32x32x16_bf16(A1, B1, mm, 0,0,0);
            float rdn = RD[32*w + l31];          // column scale (n = l31)
            char* SmW = E + 15360 + w*2560;
            #pragma unroll
            for (int p = 0; p < 16; ++p) {
                int rowp = (p&3) + 8*(p>>2) + 4*hp;
                float mval = (mm[p] + ((rowp == l31) ? 1.f : 0.f)) * rdn;
                *(unsigned short*)(SmW + rowp*80 + 2*l31) = (unsigned short)f2bf(mval);
            }
        }
        __syncthreads();

        // ---- solve: hand-unrolled over the 4 row-tiles, zero local arrays
        float macc = 0.f;
        f32x16 acc, yv;
        Frag8 tf, y0, y1, y2;

        #define LOAD_R(i)                                                        \
            do {                                                                 \
                _Pragma("unroll")                                                \
                for (int q = 0; q < 4; ++q) {                                    \
                    float4 zv = *(const float4*)(zb + 32*(i) + 8*q + 4*hp);      \
                    float4 mv = *(const float4*)(muv + 32*(i) + 8*q + 4*hp);     \
                    acc[4*q+0] = zv.x - mv.x;  acc[4*q+1] = zv.y - mv.y;         \
                    acc[4*q+2] = zv.z - mv.z;  acc[4*q+3] = zv.w - mv.w;         \
                }                                                                \
            } while (0)
        #define SQACC()                                                          \
            do {                                                                 \
                _Pragma("unroll")                                                \
                for (int p = 0; p < 16; ++p) macc += yv[p] * yv[p];              \
            } while (0)

        // i = 0
        LOAD_R(0);
        tf = build_frags(acc, hp);
        yv = m_solve(E + 15360 + 0*2560 + off, tf);
        SQACC();
        y0 = build_frags(yv, hp);
        // i = 1   (off-diag block (1,0) = blk 0)
        LOAD_R(1);
        acc = off_apply(E + 0*2560 + off, y0, acc);
        tf = build_frags(acc, hp);
        yv = m_solve(E + 15360 + 1*2560 + off, tf);
        SQACC();
        y1 = build_frags(yv, hp);
        // i = 2   (blocks (2,0)=1, (2,1)=2)
        LOAD_R(2);
        acc = off_apply(E + 1*2560 + off, y0, acc);
        acc = off_apply(E + 2*2560 + off, y1, acc);
        tf = build_frags(acc, hp);
        yv = m_solve(E + 15360 + 2*2560 + off, tf);
        SQACC();
        y2 = build_frags(yv, hp);
        // i = 3   (blocks (3,0)=3, (3,1)=4, (3,2)=5)
        LOAD_R(3);
        acc = off_apply(E + 3*2560 + off, y0, acc);
        acc = off_apply(E + 4*2560 + off, y1, acc);
        acc = off_apply(E + 5*2560 + off, y2, acc);
        tf = build_frags(acc, hp);
        yv = m_solve(E + 15360 + 3*2560 + off, tf);
        SQACC();
        #undef LOAD_R
        #undef SQACC

        macc += __shfl_xor(macc, 32, 64);        // combine row-halves per column

        const float CST = 235.2482645f;          // 128*log(2*pi)
        float lp = -0.5f * (macc + 2.f * sld + CST);
        if (k == 0) lp0 = lp; else lp1 = lp;
    }

    // ---- epilogue: prior + LSE_k(lp + logpi) - LSE_k(logpi)
    if (hp == 0) {
        float pi0 = logits_pi[c*2+0], pi1 = logits_pi[c*2+1];
        float mp = fmaxf(pi0, pi1);
        float lsepi = mp + __logf(__expf(pi0-mp) + __expf(pi1-mp));
        float t0 = lp0 + pi0, t1 = lp1 + pi1;
        float mt = fmaxf(t0, t1);
        float v = prior[c] + mt + __logf(__expf(t0-mt) + __expf(t1-mt)) - lsepi;
        out[(size_t)bcol * CC + c] = v;
    }
}

extern "C" void kernel_launch(void* const* d_in, const int* in_sizes, int n_in,
                              void* d_out, int out_size, void* d_ws, size_t ws_size,
                              hipStream_t stream) {
    const float* z         = (const float*)d_in[0];
    const float* mu        = (const float*)d_in[1];
    const float* logits_pi = (const float*)d_in[2];
    const float* covL      = (const float*)d_in[3];
    const float* prior     = (const float*)d_in[4];
    float* out = (float*)d_out;

    hipLaunchKernelGGL(mda_kernel, dim3(2*CC), dim3(256), 0, stream,
                       z, mu, logits_pi, covL, prior, out);
}